// Round 10
// baseline (129.910 us; speedup 1.0000x reference)
//
#include <hip/hip_runtime.h>
#include <hip/hip_bf16.h>
#include <stdint.h>

#define N_ROWS 8192
#define DIM    2048
#define OUTD   2048
#define NEXP   8
#define RNK    16
#define ZCOLS  128          // NEXP*RNK
#define KAUG   2176         // DIM + ZCOLS

typedef unsigned short u16;
typedef float  f32x4  __attribute__((ext_vector_type(4)));
typedef __bf16 bf16x8 __attribute__((ext_vector_type(8)));

__device__ __forceinline__ u16 f2bf(float f) {
  unsigned u = __float_as_uint(f);
  return (u16)((u + 0x7fffu + ((u >> 16) & 1u)) >> 16);   // RNE
}

#define GLOAD(SRC, DST) __builtin_amdgcn_global_load_lds( \
    (__attribute__((address_space(1))) void*)(SRC), \
    (__attribute__((address_space(3))) void*)(DST), 16, 0, 0)

// ---- K2a: Ab = bf16(lora_A flat) — only this part gates KF ----
__global__ __launch_bounds__(256) void k2a_lora(
    const float* __restrict__ lA, u16* __restrict__ ab)
{
  const int t  = threadIdx.x;
  const int ar = blockIdx.x;                // 0..127
  const float* src = lA + (size_t)ar * DIM;
  u16* dst = ab + (size_t)ar * DIM;
  #pragma unroll
  for (int i = 0; i < 2; ++i) {
    int c = t * 4 + i * 1024;
    float4 v = *(const float4*)(src + c);
    ushort4 s; s.x = f2bf(v.x); s.y = f2bf(v.y); s.z = f2bf(v.z); s.w = f2bf(v.w);
    *(ushort4*)(dst + c) = s;
  }
}

// ---- KFW: blocks 0..511 = fused x->bf16 + fp32 gates + xA MFMA + gated z.
//           blocks 512..2559 = Waug row conversion (only read by K4). ----
__global__ __launch_bounds__(256) void kfw_fused(
    const float* __restrict__ x, const float* __restrict__ gw,
    const float* __restrict__ gb, const u16* __restrict__ ab,
    u16* __restrict__ xaug,
    const float* __restrict__ W, const float* __restrict__ lB,
    u16* __restrict__ waug)
{
  const int t = threadIdx.x;

  if (blockIdx.x >= 512) {                  // ---- waug branch ----
    const int o = blockIdx.x - 512;         // 0..2047
    const float* wr = W + (size_t)o * DIM;
    u16* dst = waug + (size_t)o * KAUG;
    #pragma unroll
    for (int i = 0; i < 2; ++i) {
      int c = t * 4 + i * 1024;
      float4 v = *(const float4*)(wr + c);
      ushort4 s; s.x = f2bf(v.x); s.y = f2bf(v.y); s.z = f2bf(v.z); s.w = f2bf(v.w);
      *(ushort4*)(dst + c) = s;
    }
    if (t < ZCOLS) {
      int e = t >> 4, r = t & 15;
      dst[DIM + t] = f2bf(lB[((size_t)e * OUTD + o) * RNK + r]);
    }
    return;
  }

  // ---- KF branch (round-9 reg-staged version, one barrier per chunk) ----
  __shared__ __align__(16) u16 la[2][8192];
  __shared__ __align__(16) u16 xb[2][1024];
  __shared__ float4 gates[16];

  const int wave = t >> 6;
  const int lane = t & 63;
  const int r    = t >> 4;
  const int q    = t & 15;
  const size_t row0 = (size_t)blockIdx.x * 16;

  int lrow[4], lsch[4];
  #pragma unroll
  for (int i = 0; i < 4; ++i) {
    const int g = t + i * 256;
    lrow[i] = g >> 3;
    lsch[i] = (g & 7) ^ (lrow[i] & 7);
  }

  auto lab_load = [&](int c, int i) -> uint4 {
    return *(const uint4*)((const char*)(ab + (size_t)lrow[i] * DIM + c * 64)
                           + lsch[i] * 16);
  };

  uint4 lab[4];
  #pragma unroll
  for (int i = 0; i < 4; ++i) lab[i] = lab_load(0, i);
  float4 xv, gwv[8];
  xv = *(const float4*)(x + (row0 + r) * DIM + q * 4);
  #pragma unroll
  for (int e = 0; e < NEXP; ++e)
    gwv[e] = *(const float4*)(gw + (size_t)e * DIM + q * 4);

  float ga[NEXP] = {};
  f32x4 acc[2] = {};
  const int nfA = 2 * wave, nfB = 2 * wave + 1;

  for (int c = 0; c < 32; ++c) {
    const int C0 = c * 64;
    uint4 labn[4]; float4 xvn, gwvn[8];
    if (c + 1 < 32) {
      #pragma unroll
      for (int i = 0; i < 4; ++i) labn[i] = lab_load(c + 1, i);
      xvn = *(const float4*)(x + (row0 + r) * DIM + C0 + 64 + q * 4);
      #pragma unroll
      for (int e = 0; e < NEXP; ++e)
        gwvn[e] = *(const float4*)(gw + (size_t)e * DIM + C0 + 64 + q * 4);
    }
    __builtin_amdgcn_sched_barrier(0);

    #pragma unroll
    for (int i = 0; i < 4; ++i)
      *(uint4*)((char*)la[c & 1] + (t + i * 256) * 16) = lab[i];
    ushort4 s; s.x = f2bf(xv.x); s.y = f2bf(xv.y); s.z = f2bf(xv.z); s.w = f2bf(xv.w);
    *(ushort4*)(xaug + (row0 + r) * KAUG + C0 + q * 4) = s;
    #pragma unroll
    for (int e = 0; e < NEXP; ++e)
      ga[e] += xv.x * gwv[e].x + xv.y * gwv[e].y + xv.z * gwv[e].z + xv.w * gwv[e].w;
    {
      const int ch = q >> 1;
      const int by = r * 128 + ((ch ^ (r & 7)) * 16) + (q & 1) * 8;
      *(ushort4*)((char*)xb[c & 1] + by) = s;
    }

    asm volatile("s_waitcnt lgkmcnt(0)" ::: "memory");
    __builtin_amdgcn_sched_barrier(0);
    __builtin_amdgcn_s_barrier();

    const char* laP = (const char*)la[c & 1];
    const char* xbP = (const char*)xb[c & 1];
    #pragma unroll
    for (int ks = 0; ks < 2; ++ks) {
      const int ra = lane & 15;
      const int pa = ((ks * 4 + (lane >> 4)) ^ (ra & 7)) * 16;
      bf16x8 avf = *(const bf16x8*)(xbP + ra * 128 + pa);
      const int rbA = (lane & 15) + 16 * nfA;
      const int rbB = (lane & 15) + 16 * nfB;
      bf16x8 bvA = *(const bf16x8*)(laP + rbA * 128 + (((ks * 4 + (lane >> 4)) ^ (rbA & 7)) * 16));
      bf16x8 bvB = *(const bf16x8*)(laP + rbB * 128 + (((ks * 4 + (lane >> 4)) ^ (rbB & 7)) * 16));
      acc[0] = __builtin_amdgcn_mfma_f32_16x16x32_bf16(avf, bvA, acc[0], 0, 0, 0);
      acc[1] = __builtin_amdgcn_mfma_f32_16x16x32_bf16(avf, bvB, acc[1], 0, 0, 0);
    }

    #pragma unroll
    for (int i = 0; i < 4; ++i) lab[i] = labn[i];
    xv = xvn;
    #pragma unroll
    for (int e = 0; e < NEXP; ++e) gwv[e] = gwvn[e];
  }

  #pragma unroll
  for (int e = 0; e < NEXP; ++e) {
    float v = ga[e];
    v += __shfl_xor(v, 1); v += __shfl_xor(v, 2);
    v += __shfl_xor(v, 4); v += __shfl_xor(v, 8);
    ga[e] = v + gb[e];
  }
  if (q == 0) {
    int e0 = 0; float m0 = ga[0];
    #pragma unroll
    for (int e = 1; e < NEXP; ++e) if (ga[e] > m0) { m0 = ga[e]; e0 = e; }
    int e1 = (e0 == 0) ? 1 : 0; float m1 = ga[e1];
    #pragma unroll
    for (int e = 0; e < NEXP; ++e) if (e != e0 && ga[e] > m1) { m1 = ga[e]; e1 = e; }
    float tt  = expf(m1 - m0);
    float inv = 1.f / (1.f + tt);
    float4 gg; gg.x = inv; gg.y = tt * inv;
    gg.z = __int_as_float(e0); gg.w = __int_as_float(e1);
    gates[r] = gg;
  }
  __syncthreads();

  #pragma unroll
  for (int nfl = 0; nfl < 2; ++nfl) {
    const int e = 2 * wave + nfl;
    const int n = e * 16 + (lane & 15);
    #pragma unroll
    for (int j = 0; j < 4; ++j) {
      const int m = (lane >> 4) * 4 + j;
      float4 gg = gates[m];
      const float g = (e == __float_as_int(gg.z)) ? gg.x
                    : ((e == __float_as_int(gg.w)) ? gg.y : 0.f);
      xaug[(row0 + m) * KAUG + DIM + n] = f2bf(acc[nfl][j] * g);
    }
  }
}

// ---- K4: BM=256 BN=128 BK=32, 2-buf LDS ring (48 KiB -> 2-3 blocks/CU),
// counted vmcnt(3), R4 schedule. 8 waves (4M x 2N), per-wave 64x64.
// LDS layout per matrix: LDS-row j (128 B) = tile rows {2j, 2j+1};
// chunk pos p = c ^ (j&7), c = (R&1)*4 + kc  -> 2-way max bank alias (free).
__global__ __launch_bounds__(512, 4) void gemm_pipe2(
    const u16* __restrict__ A, int lda,
    const u16* __restrict__ Bm, int ldb,
    int Ksz, int grid_n,
    float* __restrict__ outF, int ldo, const float* __restrict__ bias)
{
  __shared__ __align__(16) u16 smem[24576];      // 48 KiB: A 2x16K @0 | B 2x8K @32768B

  const int tid  = threadIdx.x;
  const int wave = tid >> 6;
  const int lane = tid & 63;

  int bid = blockIdx.x;
  const int nwg = gridDim.x;
  if ((nwg & 7) == 0) {                          // bijective XCD swizzle
    const int cpx = nwg >> 3;
    bid = (bid & 7) * cpx + (bid >> 3);
  }
  const int tm = bid / grid_n;
  const int tn = bid % grid_n;
  const size_t row0 = (size_t)tm * 256;
  const size_t col0 = (size_t)tn * 128;

  // staging: inverse map for linear LDS chunk L (16B units):
  //   j = L>>3, p = L&7, c = p ^ (j&7), R = 2j + (c>>2), kc = c&3
  int Ra0, ka0, Ra1, ka1;
  {
    int L0 = tid, L1 = tid + 512;
    int j0 = L0 >> 3, c0 = (L0 & 7) ^ (j0 & 7);
    int j1 = L1 >> 3, c1 = (L1 & 7) ^ (j1 & 7);
    Ra0 = 2 * j0 + (c0 >> 2); ka0 = c0 & 3;
    Ra1 = 2 * j1 + (c1 >> 2); ka1 = c1 & 3;
  }
  const char* aP0 = (const char*)(A  + (row0 + (size_t)Ra0) * lda) + ka0 * 16;
  const char* aP1 = (const char*)(A  + (row0 + (size_t)Ra1) * lda) + ka1 * 16;
  const char* bP0 = (const char*)(Bm + (col0 + (size_t)Ra0) * ldb) + ka0 * 16;
  char* dA0 = (char*)smem + wave * 1024;         // + lane*16 by HW
  char* dA1 = (char*)smem + 8192 + wave * 1024;
  char* dB0 = (char*)smem + 32768 + wave * 1024;

  auto stage = [&](int tt) {
    const size_t ko = (size_t)tt * 64;           // 32 elems = 64 B per K-tile
    const int sa = (tt & 1) * 16384;
    const int sb = (tt & 1) * 8192;
    GLOAD(aP0 + ko, dA0 + sa);
    GLOAD(aP1 + ko, dA1 + sa);
    GLOAD(bP0 + ko, dB0 + sb);
  };

  // fragment reads: row R -> LDS byte j*128 + p*16, lane-constant p
  const int wm = wave >> 1, wn = wave & 1;
  const int l15 = lane & 15, l16 = lane >> 4;
  const int p   = (((l15 & 1) << 2) | l16) ^ ((l15 >> 1) & 7);
  const int offA0 = wm * 4096 + (l15 >> 1) * 128 + p * 16;
  const int offB0 = wn * 4096 + (l15 >> 1) * 128 + p * 16;

  f32x4 acc[4][4] = {};

  const int nk = Ksz / 32;                       // 68
  stage(0); stage(1);

  for (int t = 0; t < nk; ++t) {
    if (t + 1 < nk) asm volatile("s_waitcnt vmcnt(3)" ::: "memory");
    else            asm volatile("s_waitcnt vmcnt(0)" ::: "memory");
    __builtin_amdgcn_s_barrier();
    __builtin_amdgcn_sched_barrier(0);

    const char* sa = (const char*)smem + (t & 1) * 16384;
    const char* sb = (const char*)smem + 32768 + (t & 1) * 8192;

    bf16x8 av[4], bv[4];
    #pragma unroll
    for (int mf = 0; mf < 4; ++mf) av[mf] = *(const bf16x8*)(sa + offA0 + mf * 1024);
    #pragma unroll
    for (int nf = 0; nf < 4; ++nf) bv[nf] = *(const bf16x8*)(sb + offB0 + nf * 1024);

    __builtin_amdgcn_s_setprio(1);
    #pragma unroll
    for (int mf = 0; mf < 4; ++mf)
      #pragma unroll
      for (int nf = 0; nf < 4; ++nf)
        acc[mf][nf] = __builtin_amdgcn_mfma_f32_16x16x32_bf16(
            av[mf], bv[nf], acc[mf][nf], 0, 0, 0);
    __builtin_amdgcn_s_setprio(0);

    asm volatile("s_waitcnt lgkmcnt(0)" ::: "memory");
    __builtin_amdgcn_s_barrier();
    __builtin_amdgcn_sched_barrier(0);
    if (t + 2 < nk) stage(t + 2);
  }

  // epilogue: D layout col = lane&15, row = (lane>>4)*4 + j
  #pragma unroll
  for (int nf = 0; nf < 4; ++nf) {
    const size_t c = col0 + wn * 64 + nf * 16 + l15;
    const float bvv = bias[c];
    #pragma unroll
    for (int mf = 0; mf < 4; ++mf) {
      const size_t rb = row0 + wm * 64 + mf * 16 + (l16 << 2);
      #pragma unroll
      for (int j = 0; j < 4; ++j)
        outF[(rb + j) * (size_t)ldo + c] = acc[mf][nf][j] + bvv;
    }
  }
}

extern "C" void kernel_launch(void* const* d_in, const int* in_sizes, int n_in,
                              void* d_out, int out_size, void* d_ws, size_t ws_size,
                              hipStream_t stream) {
  const float* x  = (const float*)d_in[0];
  const float* W  = (const float*)d_in[1];
  const float* b  = (const float*)d_in[2];
  const float* lA = (const float*)d_in[3];
  const float* lB = (const float*)d_in[4];
  const float* gw = (const float*)d_in[5];
  const float* gb = (const float*)d_in[6];
  float* out = (float*)d_out;

  u16* xaug = (u16*)d_ws;                          // [8192][2176]
  u16* waug = xaug + (size_t)N_ROWS * KAUG;        // [2048][2176]
  u16* ab   = waug + (size_t)OUTD * KAUG;          // [128][2048]

  hipLaunchKernelGGL(k2a_lora, dim3(ZCOLS), dim3(256), 0, stream, lA, ab);
  hipLaunchKernelGGL(kfw_fused, dim3(512 + OUTD), dim3(256), 0, stream,
                     x, gw, gb, ab, xaug, W, lB, waug);
  hipLaunchKernelGGL(gemm_pipe2,
                     dim3((N_ROWS / 256) * (OUTD / 128)), dim3(512), 0, stream,
                     xaug, KAUG, waug, KAUG, KAUG, OUTD / 128,
                     out, OUTD, b);
}

// Round 11
// 119.041 us; speedup vs baseline: 1.0913x; 1.0913x over previous
//
#include <hip/hip_runtime.h>
#include <hip/hip_bf16.h>
#include <stdint.h>

#define N_ROWS 8192
#define DIM    2048
#define OUTD   2048
#define NEXP   8
#define RNK    16
#define ZCOLS  128          // NEXP*RNK
#define KAUG   2176         // DIM + ZCOLS

typedef unsigned short u16;
typedef float  f32x4  __attribute__((ext_vector_type(4)));
typedef float  f32x16 __attribute__((ext_vector_type(16)));
typedef __bf16 bf16x8 __attribute__((ext_vector_type(8)));

__device__ __forceinline__ u16 f2bf(float f) {
  unsigned u = __float_as_uint(f);
  return (u16)((u + 0x7fffu + ((u >> 16) & 1u)) >> 16);   // RNE
}

#define GLOAD(SRC, DST) __builtin_amdgcn_global_load_lds( \
    (__attribute__((address_space(1))) void*)(SRC), \
    (__attribute__((address_space(3))) void*)(DST), 16, 0, 0)

// ---- K2a: Ab = bf16(lora_A flat) — only this part gates KF ----
__global__ __launch_bounds__(256) void k2a_lora(
    const float* __restrict__ lA, u16* __restrict__ ab)
{
  const int t  = threadIdx.x;
  const int ar = blockIdx.x;                // 0..127
  const float* src = lA + (size_t)ar * DIM;
  u16* dst = ab + (size_t)ar * DIM;
  #pragma unroll
  for (int i = 0; i < 2; ++i) {
    int c = t * 4 + i * 1024;
    float4 v = *(const float4*)(src + c);
    ushort4 s; s.x = f2bf(v.x); s.y = f2bf(v.y); s.z = f2bf(v.z); s.w = f2bf(v.w);
    *(ushort4*)(dst + c) = s;
  }
}

// ---- KFW: blocks 0..511 = fused x->bf16 + fp32 gates + xA MFMA + gated z.
//           blocks 512..2559 = Waug row conversion (only read by K4). ----
__global__ __launch_bounds__(256) void kfw_fused(
    const float* __restrict__ x, const float* __restrict__ gw,
    const float* __restrict__ gb, const u16* __restrict__ ab,
    u16* __restrict__ xaug,
    const float* __restrict__ W, const float* __restrict__ lB,
    u16* __restrict__ waug)
{
  const int t = threadIdx.x;

  if (blockIdx.x >= 512) {                  // ---- waug branch ----
    const int o = blockIdx.x - 512;         // 0..2047
    const float* wr = W + (size_t)o * DIM;
    u16* dst = waug + (size_t)o * KAUG;
    #pragma unroll
    for (int i = 0; i < 2; ++i) {
      int c = t * 4 + i * 1024;
      float4 v = *(const float4*)(wr + c);
      ushort4 s; s.x = f2bf(v.x); s.y = f2bf(v.y); s.z = f2bf(v.z); s.w = f2bf(v.w);
      *(ushort4*)(dst + c) = s;
    }
    if (t < ZCOLS) {
      int e = t >> 4, r = t & 15;
      dst[DIM + t] = f2bf(lB[((size_t)e * OUTD + o) * RNK + r]);
    }
    return;
  }

  // ---- KF branch (reg-staged, one barrier per chunk) ----
  __shared__ __align__(16) u16 la[2][8192];
  __shared__ __align__(16) u16 xb[2][1024];
  __shared__ float4 gates[16];

  const int wave = t >> 6;
  const int lane = t & 63;
  const int r    = t >> 4;
  const int q    = t & 15;
  const size_t row0 = (size_t)blockIdx.x * 16;

  int lrow[4], lsch[4];
  #pragma unroll
  for (int i = 0; i < 4; ++i) {
    const int g = t + i * 256;
    lrow[i] = g >> 3;
    lsch[i] = (g & 7) ^ (lrow[i] & 7);
  }

  auto lab_load = [&](int c, int i) -> uint4 {
    return *(const uint4*)((const char*)(ab + (size_t)lrow[i] * DIM + c * 64)
                           + lsch[i] * 16);
  };

  uint4 lab[4];
  #pragma unroll
  for (int i = 0; i < 4; ++i) lab[i] = lab_load(0, i);
  float4 xv, gwv[8];
  xv = *(const float4*)(x + (row0 + r) * DIM + q * 4);
  #pragma unroll
  for (int e = 0; e < NEXP; ++e)
    gwv[e] = *(const float4*)(gw + (size_t)e * DIM + q * 4);

  float ga[NEXP] = {};
  f32x4 acc[2] = {};
  const int nfA = 2 * wave, nfB = 2 * wave + 1;

  for (int c = 0; c < 32; ++c) {
    const int C0 = c * 64;
    uint4 labn[4]; float4 xvn, gwvn[8];
    if (c + 1 < 32) {
      #pragma unroll
      for (int i = 0; i < 4; ++i) labn[i] = lab_load(c + 1, i);
      xvn = *(const float4*)(x + (row0 + r) * DIM + C0 + 64 + q * 4);
      #pragma unroll
      for (int e = 0; e < NEXP; ++e)
        gwvn[e] = *(const float4*)(gw + (size_t)e * DIM + C0 + 64 + q * 4);
    }
    __builtin_amdgcn_sched_barrier(0);

    #pragma unroll
    for (int i = 0; i < 4; ++i)
      *(uint4*)((char*)la[c & 1] + (t + i * 256) * 16) = lab[i];
    ushort4 s; s.x = f2bf(xv.x); s.y = f2bf(xv.y); s.z = f2bf(xv.z); s.w = f2bf(xv.w);
    *(ushort4*)(xaug + (row0 + r) * KAUG + C0 + q * 4) = s;
    #pragma unroll
    for (int e = 0; e < NEXP; ++e)
      ga[e] += xv.x * gwv[e].x + xv.y * gwv[e].y + xv.z * gwv[e].z + xv.w * gwv[e].w;
    {
      const int ch = q >> 1;
      const int by = r * 128 + ((ch ^ (r & 7)) * 16) + (q & 1) * 8;
      *(ushort4*)((char*)xb[c & 1] + by) = s;
    }

    asm volatile("s_waitcnt lgkmcnt(0)" ::: "memory");
    __builtin_amdgcn_sched_barrier(0);
    __builtin_amdgcn_s_barrier();

    const char* laP = (const char*)la[c & 1];
    const char* xbP = (const char*)xb[c & 1];
    #pragma unroll
    for (int ks = 0; ks < 2; ++ks) {
      const int ra = lane & 15;
      const int pa = ((ks * 4 + (lane >> 4)) ^ (ra & 7)) * 16;
      bf16x8 avf = *(const bf16x8*)(xbP + ra * 128 + pa);
      const int rbA = (lane & 15) + 16 * nfA;
      const int rbB = (lane & 15) + 16 * nfB;
      bf16x8 bvA = *(const bf16x8*)(laP + rbA * 128 + (((ks * 4 + (lane >> 4)) ^ (rbA & 7)) * 16));
      bf16x8 bvB = *(const bf16x8*)(laP + rbB * 128 + (((ks * 4 + (lane >> 4)) ^ (rbB & 7)) * 16));
      acc[0] = __builtin_amdgcn_mfma_f32_16x16x32_bf16(avf, bvA, acc[0], 0, 0, 0);
      acc[1] = __builtin_amdgcn_mfma_f32_16x16x32_bf16(avf, bvB, acc[1], 0, 0, 0);
    }

    #pragma unroll
    for (int i = 0; i < 4; ++i) lab[i] = labn[i];
    xv = xvn;
    #pragma unroll
    for (int e = 0; e < NEXP; ++e) gwv[e] = gwvn[e];
  }

  #pragma unroll
  for (int e = 0; e < NEXP; ++e) {
    float v = ga[e];
    v += __shfl_xor(v, 1); v += __shfl_xor(v, 2);
    v += __shfl_xor(v, 4); v += __shfl_xor(v, 8);
    ga[e] = v + gb[e];
  }
  if (q == 0) {
    int e0 = 0; float m0 = ga[0];
    #pragma unroll
    for (int e = 1; e < NEXP; ++e) if (ga[e] > m0) { m0 = ga[e]; e0 = e; }
    int e1 = (e0 == 0) ? 1 : 0; float m1 = ga[e1];
    #pragma unroll
    for (int e = 0; e < NEXP; ++e) if (e != e0 && ga[e] > m1) { m1 = ga[e]; e1 = e; }
    float tt  = expf(m1 - m0);
    float inv = 1.f / (1.f + tt);
    float4 gg; gg.x = inv; gg.y = tt * inv;
    gg.z = __int_as_float(e0); gg.w = __int_as_float(e1);
    gates[r] = gg;
  }
  __syncthreads();

  #pragma unroll
  for (int nfl = 0; nfl < 2; ++nfl) {
    const int e = 2 * wave + nfl;
    const int n = e * 16 + (lane & 15);
    #pragma unroll
    for (int j = 0; j < 4; ++j) {
      const int m = (lane >> 4) * 4 + j;
      float4 gg = gates[m];
      const float g = (e == __float_as_int(gg.z)) ? gg.x
                    : ((e == __float_as_int(gg.w)) ? gg.y : 0.f);
      xaug[(row0 + m) * KAUG + DIM + n] = f2bf(acc[nfl][j] * g);
    }
  }
}

// ---- K4: R4 skeleton (256x256, BK=64, 2-slot ring, vmcnt(8), 3-group) with
// 32x32x16 MFMA: 32 MFMA/wave/K-tile (half the issue slots, +15% peak rate).
// Frag map: A row=lane&31, k=(lane>>5)*8+i ; D col=lane&31,
// row=(reg&3)+8*(reg>>2)+4*(lane>>5)  [m74/m101]. LDS layout unchanged
// (row r byte r*128, chunk pos c^(r&7)); every 8 consecutive lanes cover
// r&7=0..7 -> distinct banks per cycle-group -> conflict-free.
#define MFMA32(AV, BV, ACC) \
  ACC = __builtin_amdgcn_mfma_f32_32x32x16_bf16(AV, BV, ACC, 0, 0, 0)

__global__ __launch_bounds__(512, 2) void gemm256_pipe(
    const u16* __restrict__ A, int lda,
    const u16* __restrict__ Bm, int ldb,
    int Ksz, int grid_n,
    float* __restrict__ outF, int ldo, const float* __restrict__ bias)
{
  __shared__ __align__(16) u16 smem[65536];      // 128 KiB: A[2][32K] | B[2][32K]

  const int tid  = threadIdx.x;
  const int wave = tid >> 6;
  const int lane = tid & 63;

  int bid = blockIdx.x;
  const int nwg = gridDim.x;
  if ((nwg & 7) == 0) {                          // bijective XCD swizzle
    const int cpx = nwg >> 3;
    bid = (bid & 7) * cpx + (bid >> 3);
  }
  const int tm = bid / grid_n;
  const int tn = bid % grid_n;
  const size_t row0 = (size_t)tm * 256;
  const size_t col0 = (size_t)tn * 256;

  // staging (zero-conflict family, unchanged from R4)
  const int l3  = lane >> 3;
  const int sch = ((lane & 7) ^ l3) << 4;
  const char* aSrc = (const char*)(A  + (row0 + (size_t)(wave * 8 + l3)) * lda) + sch;
  const char* bSrc = (const char*)(Bm + (col0 + (size_t)(wave * 8 + l3)) * ldb) + sch;
  const size_t arst = (size_t)lda * 128;
  const size_t brst = (size_t)ldb * 128;
  char* ldsA = (char*)smem + wave * 1024;
  char* ldsB = (char*)smem + 65536 + wave * 1024;

  auto stage = [&](int tt) {
    const size_t ko = (size_t)tt * 128;
    const int    sb = (tt & 1) << 15;
    #pragma unroll
    for (int i = 0; i < 4; ++i)
      GLOAD(aSrc + ko + i * arst, ldsA + sb + i * 8192);
    #pragma unroll
    for (int i = 0; i < 4; ++i)
      GLOAD(bSrc + ko + i * brst, ldsB + sb + i * 8192);
  };

  // fragment addressing (32x32): wave = wm (A-half) x wn (64-col quarter)
  const int wm = wave >> 2, wn = wave & 3;
  const int l31 = lane & 31, h = lane >> 5;
  int xk[4];
  #pragma unroll
  for (int ks = 0; ks < 4; ++ks)
    xk[ks] = ((ks * 2 + h) ^ (l31 & 7)) << 4;
  const int offA = wm * 16384 + l31 * 128;       // + mf*4096 + xk[ks]
  const int offB = wn * 8192  + l31 * 128;       // + nf*4096 + xk[ks]

  f32x16 acc[4][2] = {};

  const int nk = Ksz / 64;                        // 34
  stage(0); stage(1);

  for (int t = 0; t < nk; ++t) {
    if (t + 1 < nk) asm volatile("s_waitcnt vmcnt(8)" ::: "memory");
    else            asm volatile("s_waitcnt vmcnt(0)" ::: "memory");
    __builtin_amdgcn_s_barrier();
    __builtin_amdgcn_sched_barrier(0);

    const char* sa = (const char*)smem + ((t & 1) << 15);
    const char* sb = (const char*)smem + 65536 + ((t & 1) << 15);

    bf16x8 a01[4][2], b01[2][2], a23[4][2], b23[2][2];
    // ks 0-1 reads (12 b128)
    #pragma unroll
    for (int mf = 0; mf < 4; ++mf)
      #pragma unroll
      for (int ks = 0; ks < 2; ++ks)
        a01[mf][ks] = *(const bf16x8*)(sa + offA + mf * 4096 + xk[ks]);
    #pragma unroll
    for (int nf = 0; nf < 2; ++nf)
      #pragma unroll
      for (int ks = 0; ks < 2; ++ks)
        b01[nf][ks] = *(const bf16x8*)(sb + offB + nf * 4096 + xk[ks]);
    // group 1: ks0-1 x nf0 (8 MFMA)
    __builtin_amdgcn_s_setprio(1);
    #pragma unroll
    for (int ks = 0; ks < 2; ++ks)
      #pragma unroll
      for (int mf = 0; mf < 4; ++mf)
        MFMA32(a01[mf][ks], b01[0][ks], acc[mf][0]);
    __builtin_amdgcn_s_setprio(0);
    // ks 2-3 reads (12 b128) — issue overlaps group 2
    #pragma unroll
    for (int mf = 0; mf < 4; ++mf)
      #pragma unroll
      for (int ks = 0; ks < 2; ++ks)
        a23[mf][ks] = *(const bf16x8*)(sa + offA + mf * 4096 + xk[2 + ks]);
    #pragma unroll
    for (int nf = 0; nf < 2; ++nf)
      #pragma unroll
      for (int ks = 0; ks < 2; ++ks)
        b23[nf][ks] = *(const bf16x8*)(sb + offB + nf * 4096 + xk[2 + ks]);
    // group 2: ks0-1 x nf1 (8 MFMA)
    __builtin_amdgcn_s_setprio(1);
    #pragma unroll
    for (int ks = 0; ks < 2; ++ks)
      #pragma unroll
      for (int mf = 0; mf < 4; ++mf)
        MFMA32(a01[mf][ks], b01[1][ks], acc[mf][1]);
    __builtin_amdgcn_s_setprio(0);
    // slot free after all reads complete in every wave
    asm volatile("s_waitcnt lgkmcnt(0)" ::: "memory");
    __builtin_amdgcn_s_barrier();
    __builtin_amdgcn_sched_barrier(0);
    if (t + 2 < nk) stage(t + 2);
    // group 3: ks2-3 x all nf (16 MFMA) — covers staging
    __builtin_amdgcn_s_setprio(1);
    #pragma unroll
    for (int ks = 0; ks < 2; ++ks)
      #pragma unroll
      for (int nf = 0; nf < 2; ++nf)
        #pragma unroll
        for (int mf = 0; mf < 4; ++mf)
          MFMA32(a23[mf][ks], b23[nf][ks], acc[mf][nf]);
    __builtin_amdgcn_s_setprio(0);
  }

  // epilogue: D col = lane&31, row = (reg&3) + 8*(reg>>2) + 4*(lane>>5)
  #pragma unroll
  for (int nf = 0; nf < 2; ++nf) {
    const size_t c = col0 + wn * 64 + nf * 32 + l31;
    const float bvv = bias[c];
    #pragma unroll
    for (int mf = 0; mf < 4; ++mf) {
      const size_t rb = row0 + wm * 128 + mf * 32 + h * 4;
      #pragma unroll
      for (int j = 0; j < 16; ++j) {
        const size_t rr = rb + (j & 3) + 8 * (j >> 2);
        outF[rr * (size_t)ldo + c] = acc[mf][nf][j] + bvv;
      }
    }
  }
}

extern "C" void kernel_launch(void* const* d_in, const int* in_sizes, int n_in,
                              void* d_out, int out_size, void* d_ws, size_t ws_size,
                              hipStream_t stream) {
  const float* x  = (const float*)d_in[0];
  const float* W  = (const float*)d_in[1];
  const float* b  = (const float*)d_in[2];
  const float* lA = (const float*)d_in[3];
  const float* lB = (const float*)d_in[4];
  const float* gw = (const float*)d_in[5];
  const float* gb = (const float*)d_in[6];
  float* out = (float*)d_out;

  u16* xaug = (u16*)d_ws;                          // [8192][2176]
  u16* waug = xaug + (size_t)N_ROWS * KAUG;        // [2048][2176]
  u16* ab   = waug + (size_t)OUTD * KAUG;          // [128][2048]

  hipLaunchKernelGGL(k2a_lora, dim3(ZCOLS), dim3(256), 0, stream, lA, ab);
  hipLaunchKernelGGL(kfw_fused, dim3(512 + OUTD), dim3(256), 0, stream,
                     x, gw, gb, ab, xaug, W, lB, waug);
  hipLaunchKernelGGL(gemm256_pipe,
                     dim3((N_ROWS / 256) * (OUTD / 256)), dim3(512), 0, stream,
                     xaug, KAUG, waug, KAUG, KAUG, OUTD / 256,
                     out, OUTD, b);
}